// Round 7
// baseline (2601.166 us; speedup 1.0000x reference)
//
#include <hip/hip_runtime.h>

typedef float f32x4 __attribute__((ext_vector_type(4)));
typedef short bf16x8 __attribute__((ext_vector_type(8)));
typedef unsigned u32x4 __attribute__((ext_vector_type(4)));

#define N_  1024
#define T_  512
#define B_  128
#define NI_ 6
#define NO_ 2
#define NS_ 0.13416407864998738f   // sqrt(2/alpha)*sigma = sqrt(20)*0.03
#define ALPHA_ 0.1f
#define GAMMA_ 0.1f

#define NG   16                    // column groups (8 cols each)
#define CPG  8                     // cols per group
#define RPB  64                    // rows per block
#define SBG  (CPG * N_)            // uints per group slice (packed bf16 pair per elem)
#define SBT  (NG * SBG)            // uints per time buffer
#define FSTRIDE 16                 // uints per flag slot = 64 B
#define PWS  1025                  // pw column stride: 1025 mod 32 = 1 -> banks spread

#define MFMA_(A,B,C) __builtin_amdgcn_mfma_f32_16x16x32_bf16(A,B,C,0,0,0)

// pin W fragments so the compiler cannot rematerialize/spill them in-loop
#define PIN_WF() asm volatile("" \
    : "+v"(wh[0]),"+v"(wh[1]),"+v"(wh[2]),"+v"(wh[3]),"+v"(wh[4]),"+v"(wh[5]),"+v"(wh[6]),"+v"(wh[7]), \
      "+v"(wl[0]),"+v"(wl[1]),"+v"(wl[2]),"+v"(wl[3]),"+v"(wl[4]),"+v"(wl[5]),"+v"(wl[6]),"+v"(wl[7]))

__device__ __forceinline__ unsigned short f2bf(float f) {   // RNE f32->bf16
    unsigned x = __float_as_uint(f);
    return (unsigned short)((x + 0x7fffu + ((x >> 16) & 1u)) >> 16);
}
__device__ __forceinline__ float bf2f(unsigned short h) {
    return __uint_as_float(((unsigned)h) << 16);
}
// device-scope store/load: bypass L1+L2 -> coherence point visible to all XCDs
__device__ __forceinline__ void st_sys_u(unsigned* p, unsigned v) {
    asm volatile("global_store_dword %0, %1, off sc0 sc1" :: "v"(p), "v"(v) : "memory");
}
__device__ __forceinline__ unsigned ld_flag(const unsigned* p) {
    unsigned v;
    asm volatile("global_load_dword %0, %1, off sc0 sc1\n\t"
                 "s_waitcnt vmcnt(0)"
                 : "=v"(v) : "v"(p) : "memory");
    return v;
}

// build hi/lo bf16x8 fragments from 8 packed (hi<<16|lo) words (a=w0..3, b=w4..7).
// element j of fragment = value at k-offset j; dword j2 low short = elem 2j2.
union FragU { u32x4 u; bf16x8 v; };
__device__ __forceinline__ void mkfrag(u32x4 a, u32x4 b, bf16x8& hi, bf16x8& lo) {
    FragU h, l;
    h.u[0] = (a[1] & 0xFFFF0000u) | (a[0] >> 16);
    h.u[1] = (a[3] & 0xFFFF0000u) | (a[2] >> 16);
    h.u[2] = (b[1] & 0xFFFF0000u) | (b[0] >> 16);
    h.u[3] = (b[3] & 0xFFFF0000u) | (b[2] >> 16);
    l.u[0] = (a[1] << 16) | (a[0] & 0xFFFFu);
    l.u[1] = (a[3] << 16) | (a[2] & 0xFFFFu);
    l.u[2] = (b[1] << 16) | (b[0] & 0xFFFFu);
    l.u[3] = (b[3] << 16) | (b[2] & 0xFFFFu);
    hi = h.v; lo = l.v;
}

#define DO_MFMA() do { \
    _Pragma("unroll") \
    for (int mt_ = 0; mt_ < 4; ++mt_) { \
        acc[mt_] = MFMA_(wh[mt_*2+0], bh0, acc[mt_]); \
        acc[mt_] = MFMA_(wh[mt_*2+0], bl0, acc[mt_]); \
        acc[mt_] = MFMA_(wl[mt_*2+0], bh0, acc[mt_]); \
        acc[mt_] = MFMA_(wl[mt_*2+0], bl0, acc[mt_]); \
        acc[mt_] = MFMA_(wh[mt_*2+1], bh1, acc[mt_]); \
        acc[mt_] = MFMA_(wh[mt_*2+1], bl1, acc[mt_]); \
        acc[mt_] = MFMA_(wl[mt_*2+1], bh1, acc[mt_]); \
        acc[mt_] = MFMA_(wl[mt_*2+1], bl1, acc[mt_]); \
    } \
} while (0)

// 256 blocks = 16 col-groups x 16 row-blocks; 1024 threads = 16 waves.
// MFMA GEMM with persistent W hi/lo A-fragments in VGPRs. B-fragments loaded
// DIRECTLY from the packed global slice (no LDS transpose). Exchange: one flag
// post per block per step (LDS arrival counter), consumers overlap their
// poll+load+MFMA with the producers' reduce. 2 barriers/step.
__global__ __launch_bounds__(1024, 4) void rnn_kernel(
    const float* __restrict__ u,      // (NI, T, B)
    const float* __restrict__ rn,     // (N, T, B)
    const float* __restrict__ ino,    // (NI, T, B)
    const float* __restrict__ Wrec,   // (N, N)
    const float* __restrict__ Winp,   // (N, NI)
    const float* __restrict__ Wout,   // (NO, N)
    const float* __restrict__ yinit,  // (N,)
    float* __restrict__ out,          // (NO, T, B) pre-zeroed
    unsigned int* __restrict__ flags, // [g*16+R] slots, FSTRIDE apart (zeroed)
    unsigned int* __restrict__ sbuf)  // 2*SBT uints ping-pong, packed (hi<<16|lo)
{
    __shared__ float pw[CPG * PWS];         // split-K partials [c][w*64+row]  32.8 KB
    __shared__ float outL[NO_ * T_ * CPG];  // per-block out partials [o][t][c] 32 KB
    __shared__ float rnL[RPB * 9];          // padded stride 9
    __shared__ float uL[NI_ * CPG];
    __shared__ float inoL[NI_ * CPG];
    __shared__ float WinpL[RPB * 7];        // padded stride 7
    __shared__ float WoutL[NO_ * RPB];
    __shared__ unsigned scnt;               // monotonic producer-arrival counter

    const int bid  = blockIdx.x;
    const int g    = bid >> 4;            // col group
    const int R    = bid & 15;            // row block
    const int col0 = g * CPG;
    const int r0   = R * RPB;
    const int tid  = threadIdx.x;
    const int wv   = tid >> 6;            // wave = k-slice (and reduce col for wv<8)
    const int ln   = tid & 63;
    const int k0   = wv * 64;
    const int lq   = ln >> 4;             // lane quad 0..3
    const int lm   = ln & 15;             // lane mod 16
    const int cc   = ln & 7;              // B-frag col (cols 8..15 duplicate 0..7)
    const int tid3 = tid - 512;           // prefetch role: waves 8..15

    // ---- persistent W fragments: A-operand, bf16 hi/lo split, built once ----
    // mfma_f32_16x16x32_bf16 A layout: lane l holds A[m = l&15][k = (l>>4)*8 + j]
    bf16x8 wh[8], wl[8];                  // index mt*2+kt
    #pragma unroll
    for (int mt = 0; mt < 4; ++mt)
      #pragma unroll
      for (int kt = 0; kt < 2; ++kt) {
        const float* wr = Wrec + (size_t)(r0 + mt*16 + lm) * N_ + (k0 + kt*32 + lq*8);
        bf16x8 h8, l8;
        #pragma unroll
        for (int j = 0; j < 8; ++j) {
            const float v = wr[j];
            const unsigned short hb = f2bf(v);
            const unsigned short lb = f2bf(v - bf2f(hb));
            h8[j] = (short)hb; l8[j] = (short)lb;
        }
        wh[mt*2+kt] = h8; wl[mt*2+kt] = l8;
      }
    PIN_WF();

    // ---- stage small weights ----
    if (tid < RPB * NI_) {
        const int r = tid / NI_, q = tid % NI_;
        WinpL[r * 7 + q] = Winp[(r0 + r) * NI_ + q];
    }
    if (tid < NO_ * RPB)
        WoutL[tid] = Wout[(tid >> 6) * N_ + r0 + (tid & 63)];
    if (tid == 0) scnt = 0u;

    // producer state register: wave wv<8 owns (row r0+ln, col col0+wv)
    float s_prev = (wv < 8) ? yinit[r0 + ln] : 0.f;

    // ---- prefetch pointwise inputs for t=0 (waves 8..15) ----
    float pfa = 0.f, pfb = 0.f;
    if (tid3 >= 0) {
        pfa = rn[(size_t)(r0 + (tid3 >> 3)) * (T_ * B_) + col0 + (tid3 & 7)];
        if (tid3 < 2 * NI_ * CPG) {
            const int q = (tid3 >> 3) % NI_, pc = tid3 & 7;
            pfb = ((tid3 < NI_ * CPG) ? u : ino)[q * (T_ * B_) + col0 + pc];
        }
    }
    __syncthreads();   // WoutL/WinpL/scnt ready

    // ---- prologue: out[:,0,:] partials -> LDS ----
    if (wv < 8) {
        #pragma unroll
        for (int o = 0; o < NO_; ++o) {
            float pp = WoutL[o * RPB + ln] * s_prev;
            #pragma unroll
            for (int off = 32; off; off >>= 1) pp += __shfl_down(pp, off, 64);
            if (ln == 0) outL[(o << 12) | wv] = pp;
        }
    }

    // ---- prologue MFMA: fragments of s_0 built from yinit (col-broadcast) ----
    f32x4 acc[4] = {{0,0,0,0},{0,0,0,0},{0,0,0,0},{0,0,0,0}};
    {
        u32x4 a0, b0, a1, b1;
        #pragma unroll
        for (int j2 = 0; j2 < 4; ++j2) {
            #pragma unroll
            for (int kt = 0; kt < 2; ++kt) {
                const int base = k0 + kt * 32 + lq * 8;
                const float v0 = yinit[base + 2*j2];
                const float v1 = yinit[base + 2*j2 + 1];
                unsigned short h0 = f2bf(v0), h1 = f2bf(v1);
                unsigned w0 = ((unsigned)h0 << 16) | f2bf(v0 - bf2f(h0));
                unsigned w1 = ((unsigned)h1 << 16) | f2bf(v1 - bf2f(h1));
                if (j2 < 2) { if (kt == 0) { a0[2*j2] = w0; a0[2*j2+1] = w1; }
                              else        { a1[2*j2] = w0; a1[2*j2+1] = w1; } }
                else        { if (kt == 0) { b0[2*(j2-2)] = w0; b0[2*(j2-2)+1] = w1; }
                              else        { b1[2*(j2-2)] = w0; b1[2*(j2-2)+1] = w1; } }
            }
        }
        bf16x8 bh0, bl0, bh1, bl1;
        mkfrag(a0, b0, bh0, bl0);
        mkfrag(a1, b1, bh1, bl1);
        DO_MFMA();
    }

    #pragma unroll 1
    for (int t = 0; t < T_ - 1; ++t) {
        PIN_WF();
        // ---- TOP: park prefetched inputs for step t (waves 8..15) ----
        if (tid3 >= 0) {
            rnL[(tid3 >> 3) * 9 + (tid3 & 7)] = pfa;
            if (tid3 < NI_ * CPG)          uL[tid3] = pfb;
            else if (tid3 < 2 * NI_ * CPG) inoL[tid3 - NI_ * CPG] = pfb;
        }
        // ---- publish split-K partials (C/D: col=lane&15, row=(lane>>4)*4+reg) ----
        if (lm < 8) {
            #pragma unroll
            for (int mt = 0; mt < 4; ++mt)
                #pragma unroll
                for (int rg = 0; rg < 4; ++rg)
                    pw[lm * PWS + wv * 64 + mt * 16 + lq * 4 + rg] = acc[mt][rg];
        }
        __syncthreads();                    // sync1: pw + staged inputs visible

        const bool notlast = (t < T_ - 2);
        unsigned* sbn = sbuf + (size_t)((t + 1) & 1) * SBT + (size_t)g * SBG;
        const unsigned tgt = (unsigned)(t + 1);
        const unsigned* flp = flags + (size_t)(g * 16 + wv) * FSTRIDE;

        if (wv < 8) {
            // ---- reduce 16-way split-K for col (col0+wv), row (r0+ln) ----
            float hs = 0.f;
            #pragma unroll
            for (int w2 = 0; w2 < 16; ++w2) hs += pw[wv * PWS + w2 * 64 + ln];
            #pragma unroll
            for (int q = 0; q < NI_; ++q)
                hs = fmaf(WinpL[ln * 7 + q],
                          fmaf(NS_, inoL[q * CPG + wv], uL[q * CPG + wv]), hs);
            const float rhs  = -s_prev + fmaxf(0.f, hs) + NS_ * rnL[ln * 9 + wv]
                               - GAMMA_ * s_prev * s_prev * s_prev;
            const float snew = fmaf(ALPHA_, rhs, s_prev);
            s_prev = snew;
            const unsigned short hb = f2bf(snew);
            const unsigned short lb = f2bf(snew - bf2f(hb));
            if (notlast) st_sys_u(&sbn[wv * N_ + r0 + ln], ((unsigned)hb << 16) | lb);
            // out-projection partials overlap the store's flight time
            float po0 = WoutL[ln] * snew;
            float po1 = WoutL[RPB + ln] * snew;
            #pragma unroll
            for (int off = 32; off; off >>= 1) {
                po0 += __shfl_down(po0, off, 64);
                po1 += __shfl_down(po1, off, 64);
            }
            if (notlast) {
                asm volatile("s_waitcnt vmcnt(0)" ::: "memory");  // snew globally visible
                if (ln == 0) {
                    // monotonic arrival counter: 8th producer wave posts ONE flag
                    unsigned old = atomicAdd(&scnt, 1u);
                    if (old == 8u * (unsigned)t + 7u)
                        __hip_atomic_fetch_add(&flags[(size_t)(g * 16 + R) * FSTRIDE],
                                               1u, __ATOMIC_RELAXED, __HIP_MEMORY_SCOPE_AGENT);
                }
            }
            if (ln == 0) {
                outL[(0 << 12) | ((t + 1) << 3) | wv] = po0;
                outL[(1 << 12) | ((t + 1) << 3) | wv] = po1;
            }
        }

        if (notlast) {
            // ---- dataflow wait (consumers start this during the producers' reduce) ----
            while (ld_flag(flp) < tgt) __builtin_amdgcn_s_sleep(1);

            // ---- load own B-fragment slice DIRECTLY: 4x dwordx4, no LDS round trip ----
            // rows k0 + kt*32 + lq*8 + 0..7 of col cc (packed hi|lo words)
            const unsigned* up = sbn + cc * N_ + k0 + lq * 8;
            u32x4 q0, q1, q2, q3;
            asm volatile(
                "global_load_dwordx4 %0, %4, off sc0 sc1\n\t"
                "global_load_dwordx4 %1, %4, off offset:16 sc0 sc1\n\t"
                "global_load_dwordx4 %2, %4, off offset:128 sc0 sc1\n\t"
                "global_load_dwordx4 %3, %4, off offset:144 sc0 sc1\n\t"
                "s_waitcnt vmcnt(0)"
                : "=&v"(q0), "=&v"(q1), "=&v"(q2), "=&v"(q3)
                : "v"(up) : "memory");
            bf16x8 bh0, bl0, bh1, bl1;
            mkfrag(q0, q1, bh0, bl0);
            mkfrag(q2, q3, bh1, bl1);

            // ---- MFMA for step t+1 (acc carried to next TOP's pw write) ----
            #pragma unroll
            for (int mt = 0; mt < 4; ++mt) acc[mt] = (f32x4){0,0,0,0};
            DO_MFMA();

            // ---- issue input prefetch for t+1 (after the vmcnt'd load asm) ----
            if (tid3 >= 0) {
                pfa = rn[(size_t)(r0 + (tid3 >> 3)) * (T_ * B_)
                         + (size_t)(t + 1) * B_ + col0 + (tid3 & 7)];
                if (tid3 < 2 * NI_ * CPG) {
                    const int q = (tid3 >> 3) % NI_, pc = tid3 & 7;
                    pfb = ((tid3 < NI_ * CPG) ? u : ino)
                              [q * (T_ * B_) + (t + 1) * B_ + col0 + pc];
                }
            }
        }
        __syncthreads();                    // sync2: pw/parks WAR fence
    }

    // ---- flush out partials: 8192 atomics/block, off the timing-critical loop ----
    __syncthreads();
    #pragma unroll
    for (int i = 0; i < 8; ++i) {
        const int j = tid + i * 1024;
        const int o = j >> 12, tt = (j >> 3) & (T_ - 1), c = j & 7;
        atomicAdd(&out[(size_t)o * (T_ * B_) + (size_t)tt * B_ + col0 + c], outL[j]);
    }
}

extern "C" void kernel_launch(void* const* d_in, const int* in_sizes, int n_in,
                              void* d_out, int out_size, void* d_ws, size_t ws_size,
                              hipStream_t stream) {
    const float* u    = (const float*)d_in[0];
    const float* rn   = (const float*)d_in[1];
    const float* ino  = (const float*)d_in[2];
    const float* Wrec = (const float*)d_in[3];
    const float* Winp = (const float*)d_in[4];
    const float* Wout = (const float*)d_in[5];
    const float* yin  = (const float*)d_in[6];
    float* out = (float*)d_out;

    unsigned int* flags = (unsigned int*)d_ws;            // 256 slots x 64 B = 16 KB
    unsigned int* sbuf  = (unsigned int*)((char*)d_ws + 32768);  // 1 MB ping-pong

    hipMemsetAsync(d_ws, 0, 32768, stream);
    hipMemsetAsync(d_out, 0, (size_t)out_size * sizeof(float), stream);

    void* args[] = {(void*)&u, (void*)&rn, (void*)&ino, (void*)&Wrec, (void*)&Winp,
                    (void*)&Wout, (void*)&yin, (void*)&out, (void*)&flags, (void*)&sbuf};
    hipLaunchCooperativeKernel((void*)rnn_kernel, dim3(256), dim3(1024), args, 0, stream);
}